// Round 1
// baseline (1620.087 us; speedup 1.0000x reference)
//
#include <hip/hip_runtime.h>
#include <hip/hip_bf16.h>

// GIN: h1 = relu(x@W1 + agg(x@W1) + b1); h2 = relu(h1@W2 + agg(h1@W2) + b2);
// out = (meanpool(h2)) @ W3 + b3
// Uses linearity: agg(x)@W == agg(x@W), so GEMM first, then scatter on z.

#define N_FEAT 64

// z[i][c] = sum_k X[i][k] * W[k][c]   (64x64 W cached in LDS)
__global__ void gemm64(const float* __restrict__ X, const float* __restrict__ W,
                       float* __restrict__ Z, int nrows) {
    __shared__ float sW[64 * 64];
    __shared__ float sX[4][64];
    int tid = threadIdx.x;
    for (int i = tid; i < 64 * 64; i += 256) sW[i] = W[i];
    int r = tid >> 6;   // 0..3
    int c = tid & 63;
    int row = blockIdx.x * 4 + r;
    if (row < nrows) sX[r][c] = X[row * 64 + c];
    __syncthreads();
    if (row < nrows) {
        float acc = 0.f;
#pragma unroll
        for (int k = 0; k < 64; ++k) acc += sX[r][k] * sW[k * 64 + c];
        Z[row * 64 + c] = acc;
    }
}

// for each edge e: agg[dst[e]] += Z[src[e]]  (16 threads/edge, float4 chunks)
__global__ void scatter_agg(const float* __restrict__ Z, const int* __restrict__ src,
                            const int* __restrict__ dst, float* __restrict__ agg,
                            int nedges) {
    int gid = blockIdx.x * blockDim.x + threadIdx.x;
    int e = gid >> 4;
    if (e >= nedges) return;
    int c4 = gid & 15;
    int s = src[e];
    int d = dst[e];
    float4 v = reinterpret_cast<const float4*>(Z + (size_t)s * 64)[c4];
    float* p = agg + (size_t)d * 64 + c4 * 4;
    atomicAdd(p + 0, v.x);
    atomicAdd(p + 1, v.y);
    atomicAdd(p + 2, v.z);
    atomicAdd(p + 3, v.w);
}

// H = relu(Z + A + bias)   (elementwise over nodes*64, float4)
__global__ void add_bias_relu(const float* __restrict__ Z, const float* __restrict__ A,
                              const float* __restrict__ bias, float* __restrict__ H,
                              int n4 /* nodes*16 */) {
    int gid = blockIdx.x * blockDim.x + threadIdx.x;
    if (gid >= n4) return;
    int c4 = gid & 15;
    float4 z = reinterpret_cast<const float4*>(Z)[gid];
    float4 a = reinterpret_cast<const float4*>(A)[gid];
    float4 b = reinterpret_cast<const float4*>(bias)[c4];
    float4 h;
    h.x = fmaxf(z.x + a.x + b.x, 0.f);
    h.y = fmaxf(z.y + a.y + b.y, 0.f);
    h.z = fmaxf(z.z + a.z + b.z, 0.f);
    h.w = fmaxf(z.w + a.w + b.w, 0.f);
    reinterpret_cast<float4*>(H)[gid] = h;
}

// sums[batch[i]] += H[i]; cnt[batch[i]] += 1
__global__ void pool_scatter(const float* __restrict__ H, const int* __restrict__ batch,
                             float* __restrict__ sums, float* __restrict__ cnt,
                             int nnodes) {
    int gid = blockIdx.x * blockDim.x + threadIdx.x;
    int node = gid >> 4;
    if (node >= nnodes) return;
    int c4 = gid & 15;
    int g = batch[node];
    float4 v = reinterpret_cast<const float4*>(H + (size_t)node * 64)[c4];
    float* p = sums + (size_t)g * 64 + c4 * 4;
    atomicAdd(p + 0, v.x);
    atomicAdd(p + 1, v.y);
    atomicAdd(p + 2, v.z);
    atomicAdd(p + 3, v.w);
    if (c4 == 0) atomicAdd(cnt + g, 1.0f);
}

// out[g][c] = (sums[g] . W3[:,c]) / max(cnt[g],1) + b3[c]
__global__ void final_head(const float* __restrict__ sums, const float* __restrict__ cnt,
                           const float* __restrict__ W3, const float* __restrict__ b3,
                           float* __restrict__ out, int nclasses) {
    int g = blockIdx.x;
    int t = threadIdx.x;
    __shared__ float row[64];
    row[t] = sums[(size_t)g * 64 + t];
    __syncthreads();
    if (t < nclasses) {
        float acc = 0.f;
#pragma unroll
        for (int k = 0; k < 64; ++k) acc += row[k] * W3[k * nclasses + t];
        float den = fmaxf(cnt[g], 1.0f);
        out[g * nclasses + t] = acc / den + b3[t];
    }
}

extern "C" void kernel_launch(void* const* d_in, const int* in_sizes, int n_in,
                              void* d_out, int out_size, void* d_ws, size_t ws_size,
                              hipStream_t stream) {
    const float* x     = (const float*)d_in[0];
    const int*   ei    = (const int*)d_in[1];   // [2, E]
    const int*   batch = (const int*)d_in[2];
    const float* W1    = (const float*)d_in[3];
    const float* b1    = (const float*)d_in[4];
    const float* W2    = (const float*)d_in[5];
    const float* b2    = (const float*)d_in[6];
    const float* W3    = (const float*)d_in[7];
    const float* b3    = (const float*)d_in[8];
    float* out = (float*)d_out;

    const int N = in_sizes[0] / N_FEAT;       // 50000
    const int E = in_sizes[1] / 2;            // 800000
    const int NCLS = 10;
    const int G = out_size / NCLS;            // 500
    const int* src = ei;
    const int* dst = ei + E;

    float* z    = (float*)d_ws;               // N*64
    float* agg  = z + (size_t)N * 64;         // N*64
    float* h    = agg + (size_t)N * 64;       // N*64
    float* sums = h + (size_t)N * 64;         // G*64
    float* cnt  = sums + (size_t)G * 64;      // G

    const int gemmGrid = (N + 3) / 4;
    const int edgeThreads = E * 16;
    const int edgeGrid = (edgeThreads + 255) / 256;
    const int elemThreads = N * 16;
    const int elemGrid = (elemThreads + 255) / 256;

    // ---- layer 1 ----
    hipMemsetAsync(agg, 0, (size_t)N * 64 * sizeof(float), stream);
    gemm64<<<gemmGrid, 256, 0, stream>>>(x, W1, z, N);
    scatter_agg<<<edgeGrid, 256, 0, stream>>>(z, src, dst, agg, E);
    add_bias_relu<<<elemGrid, 256, 0, stream>>>(z, agg, b1, h, elemThreads);

    // ---- layer 2 ----
    hipMemsetAsync(agg, 0, (size_t)N * 64 * sizeof(float), stream);
    gemm64<<<gemmGrid, 256, 0, stream>>>(h, W2, z, N);
    scatter_agg<<<edgeGrid, 256, 0, stream>>>(z, src, dst, agg, E);
    add_bias_relu<<<elemGrid, 256, 0, stream>>>(z, agg, b2, h, elemThreads);

    // ---- pool + head ----
    hipMemsetAsync(sums, 0, ((size_t)G * 64 + G) * sizeof(float), stream);
    pool_scatter<<<elemGrid, 256, 0, stream>>>(h, batch, sums, cnt, N);
    final_head<<<G, 64, 0, stream>>>(sums, cnt, W3, b3, out, NCLS);
}

// Round 2
// 510.214 us; speedup vs baseline: 3.1753x; 3.1753x over previous
//
#include <hip/hip_runtime.h>
#include <hip/hip_bf16.h>

// GIN via linearity: agg(x)@W == agg(x@W). Per layer: z = X@W (dense GEMM),
// then h = relu(z + gather_sum(z over in-edges) + b) using a CSR built
// on-device (dst-bucketed). No float atomics anywhere.

#define N_FEAT 64

// ---- GEMM: 64 rows per block, 256 threads, W + X tile in LDS ----
__global__ void gemm64(const float* __restrict__ X, const float* __restrict__ W,
                       float* __restrict__ Z, int nrows) {
    __shared__ float sW[64 * 64];
    __shared__ float sX[64][64];
    int tid = threadIdx.x;
    int c = tid & 63;
    int rg = tid >> 6;          // 0..3
    for (int i = tid; i < 64 * 64; i += 256) sW[i] = W[i];
    int base = blockIdx.x * 64;
    for (int r = rg; r < 64; r += 4) {
        int row = base + r;
        sX[r][c] = (row < nrows) ? X[(size_t)row * 64 + c] : 0.f;
    }
    __syncthreads();
#pragma unroll
    for (int t = 0; t < 16; ++t) {
        int r = t * 4 + rg;
        float acc = 0.f;
#pragma unroll
        for (int k = 0; k < 64; ++k) acc += sX[r][k] * sW[k * 64 + c];
        int row = base + r;
        if (row < nrows) Z[(size_t)row * 64 + c] = acc;
    }
}

// ---- CSR build ----
__global__ void hist_deg(const int* __restrict__ dst, int* __restrict__ deg, int E) {
    int e = blockIdx.x * blockDim.x + threadIdx.x;
    if (e < E) atomicAdd(&deg[dst[e]], 1);
}

// single-block exclusive scan of deg[0..n) -> rowptr[0..n], rowptr[n]=total
__global__ void scan_deg(const int* __restrict__ deg, int* __restrict__ rowptr, int n) {
    __shared__ int s[1024];
    int tid = threadIdx.x;
    int chunk = (n + 1023) >> 10;
    int lo = tid * chunk;
    int hi = min(lo + chunk, n);
    int sum = 0;
    for (int i = lo; i < hi; ++i) sum += deg[i];
    s[tid] = sum;
    __syncthreads();
    for (int off = 1; off < 1024; off <<= 1) {
        int v = (tid >= off) ? s[tid - off] : 0;
        __syncthreads();
        s[tid] += v;
        __syncthreads();
    }
    int run = (tid == 0) ? 0 : s[tid - 1];
    for (int i = lo; i < hi; ++i) { rowptr[i] = run; run += deg[i]; }
    if (tid == 0) rowptr[n] = s[1023];
}

__global__ void fill_csr(const int* __restrict__ src, const int* __restrict__ dst,
                         int* __restrict__ cursor, int* __restrict__ col, int E) {
    int e = blockIdx.x * blockDim.x + threadIdx.x;
    if (e < E) {
        int pos = atomicAdd(&cursor[dst[e]], 1);
        col[pos] = src[e];
    }
}

// ---- gather aggregation + bias + relu fused ----
// one wave(64) per node; thread c owns channel c.
__global__ void gather_relu(const float* __restrict__ Z, const int* __restrict__ rowptr,
                            const int* __restrict__ col, const float* __restrict__ bias,
                            float* __restrict__ H, int n) {
    int node = blockIdx.x * 4 + (threadIdx.x >> 6);
    int c = threadIdx.x & 63;
    if (node >= n) return;
    int lo = rowptr[node], hi = rowptr[node + 1];
    float acc = 0.f;
    for (int j = lo; j < hi; ++j) {
        int s = col[j];                       // wave-uniform
        acc += Z[(size_t)s * 64 + c];
    }
    float v = Z[(size_t)node * 64 + c] + acc + bias[c];
    H[(size_t)node * 64 + c] = fmaxf(v, 0.f);
}

// ---- fused mean-pool + linear head (batch is sorted) ----
__global__ void pool_head(const float* __restrict__ H, const int* __restrict__ batch,
                          const float* __restrict__ W3, const float* __restrict__ b3,
                          float* __restrict__ out, int n, int ncls) {
    int g = blockIdx.x;
    __shared__ int bounds[2];
    __shared__ float row[64];
    int c = threadIdx.x;
    if (c < 2) {
        int target = g + c;                   // lower_bound(batch, target)
        int lo = 0, hi = n;
        while (lo < hi) { int m = (lo + hi) >> 1; if (batch[m] < target) lo = m + 1; else hi = m; }
        bounds[c] = lo;
    }
    __syncthreads();
    int lo = bounds[0], hi = bounds[1];
    float acc = 0.f;
    for (int i = lo; i < hi; ++i) acc += H[(size_t)i * 64 + c];
    float cntf = (float)(hi - lo);
    row[c] = acc / fmaxf(cntf, 1.0f);
    __syncthreads();
    if (c < ncls) {
        float o = b3[c];
#pragma unroll
        for (int k = 0; k < 64; ++k) o += row[k] * W3[k * ncls + c];
        out[g * ncls + c] = o;
    }
}

extern "C" void kernel_launch(void* const* d_in, const int* in_sizes, int n_in,
                              void* d_out, int out_size, void* d_ws, size_t ws_size,
                              hipStream_t stream) {
    const float* x     = (const float*)d_in[0];
    const int*   ei    = (const int*)d_in[1];   // [2, E]
    const int*   batch = (const int*)d_in[2];
    const float* W1    = (const float*)d_in[3];
    const float* b1    = (const float*)d_in[4];
    const float* W2    = (const float*)d_in[5];
    const float* b2    = (const float*)d_in[6];
    const float* W3    = (const float*)d_in[7];
    const float* b3    = (const float*)d_in[8];
    float* out = (float*)d_out;

    const int N = in_sizes[0] / N_FEAT;       // 50000
    const int E = in_sizes[1] / 2;            // 800000
    const int NCLS = 10;
    const int G = out_size / NCLS;            // 500
    const int* src = ei;
    const int* dst = ei + E;

    // workspace layout
    float* zbuf  = (float*)d_ws;                          // N*64 f32
    float* hbuf  = zbuf + (size_t)N * 64;                 // N*64 f32
    int*   rowptr = (int*)(hbuf + (size_t)N * 64);        // N+1 ints
    int*   deg    = rowptr + (N + 1);                     // N ints
    int*   cursor = deg + N;                              // N ints
    int*   col    = cursor + N;                           // E ints

    const int edgeGrid = (E + 255) / 256;
    const int gemmGrid = (N + 63) / 64;
    const int gatherGrid = (N + 3) / 4;

    // ---- build CSR (per launch; same work every call) ----
    hipMemsetAsync(deg, 0, (size_t)N * sizeof(int), stream);
    hist_deg<<<edgeGrid, 256, 0, stream>>>(dst, deg, E);
    scan_deg<<<1, 1024, 0, stream>>>(deg, rowptr, N);
    hipMemcpyAsync(cursor, rowptr, (size_t)N * sizeof(int), hipMemcpyDeviceToDevice, stream);
    fill_csr<<<edgeGrid, 256, 0, stream>>>(src, dst, cursor, col, E);

    // ---- layer 1 ----
    gemm64<<<gemmGrid, 256, 0, stream>>>(x, W1, zbuf, N);
    gather_relu<<<gatherGrid, 256, 0, stream>>>(zbuf, rowptr, col, b1, hbuf, N);

    // ---- layer 2 ----
    gemm64<<<gemmGrid, 256, 0, stream>>>(hbuf, W2, zbuf, N);
    gather_relu<<<gatherGrid, 256, 0, stream>>>(zbuf, rowptr, col, b2, hbuf, N);

    // ---- pool + head ----
    pool_head<<<G, 64, 0, stream>>>(hbuf, batch, W3, b3, out, N, NCLS);
}

// Round 3
// 326.558 us; speedup vs baseline: 4.9611x; 1.5624x over previous
//
#include <hip/hip_runtime.h>
#include <hip/hip_bf16.h>

// GIN via linearity: agg(x)@W == agg(x@W). Per layer: z = X@W (dense GEMM),
// then h = relu(z + gather_sum(z over in-edges) + b) using a CSR built
// on-device (dst-bucketed). No float atomics.
// Gather: 1 wave/node, 4 lane-groups x float4 -> 8 edge rows in flight.

#define N_FEAT 64

// ---- GEMM: 64 rows per block, 256 threads, W + X tile in LDS ----
__global__ void gemm64(const float* __restrict__ X, const float* __restrict__ W,
                       float* __restrict__ Z, int nrows) {
    __shared__ float sW[64 * 64];
    __shared__ float sX[64][64];
    int tid = threadIdx.x;
    int c = tid & 63;
    int rg = tid >> 6;          // 0..3 (wave id)
    for (int i = tid; i < 64 * 64; i += 256) sW[i] = W[i];
    int base = blockIdx.x * 64;
    for (int r = rg; r < 64; r += 4) {
        int row = base + r;
        sX[r][c] = (row < nrows) ? X[(size_t)row * 64 + c] : 0.f;
    }
    __syncthreads();
#pragma unroll
    for (int t = 0; t < 16; ++t) {
        int r = t * 4 + rg;
        float acc = 0.f;
#pragma unroll
        for (int k = 0; k < 64; ++k) acc += sX[r][k] * sW[k * 64 + c];
        int row = base + r;
        if (row < nrows) Z[(size_t)row * 64 + c] = acc;
    }
}

// ---- CSR build ----
__global__ void hist_deg(const int* __restrict__ dst, int* __restrict__ deg, int E) {
    int e = blockIdx.x * blockDim.x + threadIdx.x;
    if (e < E) atomicAdd(&deg[dst[e]], 1);
}

// per-block (256 elts) partial sums
__global__ void scan_partial(const int* __restrict__ deg, int* __restrict__ partials, int n) {
    __shared__ int s[256];
    int t = threadIdx.x;
    int i = blockIdx.x * 256 + t;
    s[t] = (i < n) ? deg[i] : 0;
    __syncthreads();
    for (int off = 128; off > 0; off >>= 1) {
        if (t < off) s[t] += s[t + off];
        __syncthreads();
    }
    if (t == 0) partials[blockIdx.x] = s[0];
}

// exclusive-scan the (<=256) partials in place; rowptr[n] = total
__global__ void scan_offsets(int* __restrict__ partials, int nb,
                             int* __restrict__ rowptr, int n) {
    __shared__ int s[256];
    int t = threadIdx.x;
    int orig = (t < nb) ? partials[t] : 0;
    s[t] = orig;
    __syncthreads();
    for (int off = 1; off < 256; off <<= 1) {
        int v = (t >= off) ? s[t - off] : 0;
        __syncthreads();
        s[t] += v;
        __syncthreads();
    }
    if (t < nb) partials[t] = s[t] - orig;      // exclusive
    if (t == 255) rowptr[n] = s[255];           // grand total
}

// final: per-block exclusive scan + block offset -> rowptr and cursor
__global__ void scan_final(const int* __restrict__ deg, const int* __restrict__ partials,
                           int* __restrict__ rowptr, int* __restrict__ cursor, int n) {
    __shared__ int s[256];
    int t = threadIdx.x;
    int i = blockIdx.x * 256 + t;
    int v = (i < n) ? deg[i] : 0;
    s[t] = v;
    __syncthreads();
    for (int off = 1; off < 256; off <<= 1) {
        int u = (t >= off) ? s[t - off] : 0;
        __syncthreads();
        s[t] += u;
        __syncthreads();
    }
    if (i < n) {
        int excl = s[t] - v + partials[blockIdx.x];
        rowptr[i] = excl;
        cursor[i] = excl;
    }
}

__global__ void fill_csr(const int* __restrict__ src, const int* __restrict__ dst,
                         int* __restrict__ cursor, int* __restrict__ col, int E) {
    int e = blockIdx.x * blockDim.x + threadIdx.x;
    if (e < E) {
        int pos = atomicAdd(&cursor[dst[e]], 1);
        col[pos] = src[e];
    }
}

// ---- gather aggregation + bias + relu, fused; 1 wave per node ----
// lane = g*16 + l : group g handles edge j+g, lane-chunk l loads float4.
__global__ void gather_relu(const float* __restrict__ Z, const int* __restrict__ rowptr,
                            const int* __restrict__ col, const float* __restrict__ bias,
                            float* __restrict__ H, int n) {
    int node = (int)((blockIdx.x * blockDim.x + threadIdx.x) >> 6);
    if (node >= n) return;                        // wave-uniform
    int lane = threadIdx.x & 63;
    int g = lane >> 4;
    int l = lane & 15;
    int lo = rowptr[node], hi = rowptr[node + 1];
    float4 acc = make_float4(0.f, 0.f, 0.f, 0.f);
    const float4* Z4 = reinterpret_cast<const float4*>(Z);
    for (int j = lo; j < hi; j += 8) {
        int j0 = j + g, j1 = j + 4 + g;
        float4 v0 = make_float4(0.f, 0.f, 0.f, 0.f);
        float4 v1 = make_float4(0.f, 0.f, 0.f, 0.f);
        if (j0 < hi) { int s = col[j0]; v0 = Z4[(size_t)s * 16 + l]; }
        if (j1 < hi) { int s = col[j1]; v1 = Z4[(size_t)s * 16 + l]; }
        acc.x += v0.x + v1.x;
        acc.y += v0.y + v1.y;
        acc.z += v0.z + v1.z;
        acc.w += v0.w + v1.w;
    }
    // reduce the 4 groups: xor 16 then 32
    acc.x += __shfl_xor(acc.x, 16); acc.y += __shfl_xor(acc.y, 16);
    acc.z += __shfl_xor(acc.z, 16); acc.w += __shfl_xor(acc.w, 16);
    acc.x += __shfl_xor(acc.x, 32); acc.y += __shfl_xor(acc.y, 32);
    acc.z += __shfl_xor(acc.z, 32); acc.w += __shfl_xor(acc.w, 32);
    if (g == 0) {
        float4 self = Z4[(size_t)node * 16 + l];
        float4 b = reinterpret_cast<const float4*>(bias)[l];
        float4 o;
        o.x = fmaxf(self.x + acc.x + b.x, 0.f);
        o.y = fmaxf(self.y + acc.y + b.y, 0.f);
        o.z = fmaxf(self.z + acc.z + b.z, 0.f);
        o.w = fmaxf(self.w + acc.w + b.w, 0.f);
        reinterpret_cast<float4*>(H)[(size_t)node * 16 + l] = o;
    }
}

// ---- fused mean-pool + linear head (batch is sorted) ----
__global__ void pool_head(const float* __restrict__ H, const int* __restrict__ batch,
                          const float* __restrict__ W3, const float* __restrict__ b3,
                          float* __restrict__ out, int n, int ncls) {
    int gidx = blockIdx.x;
    __shared__ int bounds[2];
    __shared__ float row[64];
    int lane = threadIdx.x;                 // 64
    int g = lane >> 4, l = lane & 15;
    if (lane < 2) {
        int target = gidx + lane;           // lower_bound(batch, target)
        int lo = 0, hi = n;
        while (lo < hi) { int m = (lo + hi) >> 1; if (batch[m] < target) lo = m + 1; else hi = m; }
        bounds[lane] = lo;
    }
    __syncthreads();
    int lo = bounds[0], hi = bounds[1];
    const float4* H4 = reinterpret_cast<const float4*>(H);
    float4 acc = make_float4(0.f, 0.f, 0.f, 0.f);
    for (int i = lo + g; i < hi; i += 4) {
        float4 v = H4[(size_t)i * 16 + l];
        acc.x += v.x; acc.y += v.y; acc.z += v.z; acc.w += v.w;
    }
    acc.x += __shfl_xor(acc.x, 16); acc.y += __shfl_xor(acc.y, 16);
    acc.z += __shfl_xor(acc.z, 16); acc.w += __shfl_xor(acc.w, 16);
    acc.x += __shfl_xor(acc.x, 32); acc.y += __shfl_xor(acc.y, 32);
    acc.z += __shfl_xor(acc.z, 32); acc.w += __shfl_xor(acc.w, 32);
    float inv = 1.0f / fmaxf((float)(hi - lo), 1.0f);
    if (g == 0) {
        row[l * 4 + 0] = acc.x * inv;
        row[l * 4 + 1] = acc.y * inv;
        row[l * 4 + 2] = acc.z * inv;
        row[l * 4 + 3] = acc.w * inv;
    }
    __syncthreads();
    if (lane < ncls) {
        float o = b3[lane];
#pragma unroll
        for (int k = 0; k < 64; ++k) o += row[k] * W3[k * ncls + lane];
        out[gidx * ncls + lane] = o;
    }
}

extern "C" void kernel_launch(void* const* d_in, const int* in_sizes, int n_in,
                              void* d_out, int out_size, void* d_ws, size_t ws_size,
                              hipStream_t stream) {
    const float* x     = (const float*)d_in[0];
    const int*   ei    = (const int*)d_in[1];   // [2, E]
    const int*   batch = (const int*)d_in[2];
    const float* W1    = (const float*)d_in[3];
    const float* b1    = (const float*)d_in[4];
    const float* W2    = (const float*)d_in[5];
    const float* b2    = (const float*)d_in[6];
    const float* W3    = (const float*)d_in[7];
    const float* b3    = (const float*)d_in[8];
    float* out = (float*)d_out;

    const int N = in_sizes[0] / N_FEAT;       // 50000
    const int E = in_sizes[1] / 2;            // 800000
    const int NCLS = 10;
    const int G = out_size / NCLS;            // 500
    const int* src = ei;
    const int* dst = ei + E;

    // workspace layout
    float* zbuf   = (float*)d_ws;                         // N*64 f32
    float* hbuf   = zbuf + (size_t)N * 64;                // N*64 f32
    int*   rowptr = (int*)(hbuf + (size_t)N * 64);        // N+1
    int*   deg    = rowptr + (N + 1);                     // N
    int*   cursor = deg + N;                              // N
    int*   col    = cursor + N;                           // E
    int*   partials = col + E;                            // <=256

    const int edgeGrid = (E + 255) / 256;
    const int gemmGrid = (N + 63) / 64;
    const int gatherGrid = (N + 3) / 4;
    const int nb = (N + 255) / 256;           // 196 scan blocks

    // ---- build CSR ----
    hipMemsetAsync(deg, 0, (size_t)N * sizeof(int), stream);
    hist_deg<<<edgeGrid, 256, 0, stream>>>(dst, deg, E);
    scan_partial<<<nb, 256, 0, stream>>>(deg, partials, N);
    scan_offsets<<<1, 256, 0, stream>>>(partials, nb, rowptr, N);
    scan_final<<<nb, 256, 0, stream>>>(deg, partials, rowptr, cursor, N);
    fill_csr<<<edgeGrid, 256, 0, stream>>>(src, dst, cursor, col, E);

    // ---- layer 1 ----
    gemm64<<<gemmGrid, 256, 0, stream>>>(x, W1, zbuf, N);
    gather_relu<<<gatherGrid, 256, 0, stream>>>(zbuf, rowptr, col, b1, hbuf, N);

    // ---- layer 2 ----
    gemm64<<<gemmGrid, 256, 0, stream>>>(hbuf, W2, zbuf, N);
    gather_relu<<<gatherGrid, 256, 0, stream>>>(zbuf, rowptr, col, b2, hbuf, N);

    // ---- pool + head ----
    pool_head<<<G, 64, 0, stream>>>(hbuf, batch, W3, b3, out, N, NCLS);
}

// Round 4
// 304.370 us; speedup vs baseline: 5.3228x; 1.0729x over previous
//
#include <hip/hip_runtime.h>
#include <hip/hip_bf16.h>
#include <hip/hip_fp16.h>

// GIN via linearity: agg(x)@W == agg(x@W). Per layer: z = X@W (fp32 compute,
// fp16 store), then h = relu(z + gather_sum(z) + b) via on-device CSR.
// CSR fill is a 2-pass bucket sort (coarse dst>>8 buckets) to keep scatter
// writes cache-local (the 1-pass version had 16x write amplification).

#define N_FEAT 64

// ---- GEMM: 64 rows per block, 256 threads, W + X tile in LDS; fp16 out ----
template <typename TIN>
__global__ void gemm64(const TIN* __restrict__ X, const float* __restrict__ W,
                       __half* __restrict__ Z, int nrows) {
    __shared__ float sW[64 * 64];
    __shared__ float sX[64][64];
    int tid = threadIdx.x;
    int c = tid & 63;
    int rg = tid >> 6;          // 0..3 (wave id)
    for (int i = tid; i < 64 * 64; i += 256) sW[i] = W[i];
    int base = blockIdx.x * 64;
    for (int r = rg; r < 64; r += 4) {
        int row = base + r;
        sX[r][c] = (row < nrows) ? (float)X[(size_t)row * 64 + c] : 0.f;
    }
    __syncthreads();
#pragma unroll
    for (int t = 0; t < 16; ++t) {
        int r = t * 4 + rg;
        float acc = 0.f;
#pragma unroll
        for (int k = 0; k < 64; ++k) acc += sX[r][k] * sW[k * 64 + c];
        int row = base + r;
        if (row < nrows) Z[(size_t)row * 64 + c] = __float2half(acc);
    }
}

// ---- CSR build ----
__global__ void hist_deg(const int* __restrict__ dst, int* __restrict__ deg, int E) {
    int e = blockIdx.x * blockDim.x + threadIdx.x;
    if (e < E) atomicAdd(&deg[dst[e]], 1);
}

// per-block (256 nodes) partial sums == coarse bucket totals
__global__ void scan_partial(const int* __restrict__ deg, int* __restrict__ partials, int n) {
    __shared__ int s[256];
    int t = threadIdx.x;
    int i = blockIdx.x * 256 + t;
    s[t] = (i < n) ? deg[i] : 0;
    __syncthreads();
    for (int off = 128; off > 0; off >>= 1) {
        if (t < off) s[t] += s[t + off];
        __syncthreads();
    }
    if (t == 0) partials[blockIdx.x] = s[0];
}

// exclusive-scan partials; also init coarse cursors and totals
__global__ void scan_offsets(int* __restrict__ partials, int nb, int* __restrict__ ccur,
                             int* __restrict__ rowptr, int n, int E) {
    __shared__ int s[256];
    int t = threadIdx.x;
    int orig = (t < nb) ? partials[t] : 0;
    s[t] = orig;
    __syncthreads();
    for (int off = 1; off < 256; off <<= 1) {
        int v = (t >= off) ? s[t - off] : 0;
        __syncthreads();
        s[t] += v;
        __syncthreads();
    }
    if (t < nb) {
        int excl = s[t] - orig;
        partials[t] = excl;     // bucket start offsets
        ccur[t] = excl;         // pass-A cursors
    }
    if (t == 0) { rowptr[n] = E; partials[nb] = E; }
}

// final: per-node exclusive scan + block offset -> rowptr and cursor
__global__ void scan_final(const int* __restrict__ deg, const int* __restrict__ partials,
                           int* __restrict__ rowptr, int* __restrict__ cursor, int n) {
    __shared__ int s[256];
    int t = threadIdx.x;
    int i = blockIdx.x * 256 + t;
    int v = (i < n) ? deg[i] : 0;
    s[t] = v;
    __syncthreads();
    for (int off = 1; off < 256; off <<= 1) {
        int u = (t >= off) ? s[t - off] : 0;
        __syncthreads();
        s[t] += u;
        __syncthreads();
    }
    if (i < n) {
        int excl = s[t] - v + partials[blockIdx.x];
        rowptr[i] = excl;
        cursor[i] = excl;
    }
}

// pass A: coarse-bucket (src,dst) pairs into staging; per-block LDS histogram
// so each block writes ~contiguous chunks per bucket.
#define CHUNK 2048
__global__ void bucket_scatter(const int* __restrict__ src, const int* __restrict__ dst,
                               int* __restrict__ ccur, int2* __restrict__ staging, int E) {
    __shared__ int hist[256];
    __shared__ int base[256];
    int t = threadIdx.x;
    hist[t] = 0;
    int begin = blockIdx.x * CHUNK;
    int end = min(begin + CHUNK, E);
    __syncthreads();
    for (int i = begin + t; i < end; i += 256)
        atomicAdd(&hist[dst[i] >> 8], 1);
    __syncthreads();
    int h = hist[t];
    if (h > 0) base[t] = atomicAdd(&ccur[t], h);
    __syncthreads();
    hist[t] = 0;
    __syncthreads();
    for (int i = begin + t; i < end; i += 256) {
        int d = dst[i];
        int b = d >> 8;
        int p = base[b] + atomicAdd(&hist[b], 1);
        staging[p] = make_int2(src[i], d);
    }
}

// pass B: one block per coarse bucket; fine scatter into this bucket's
// 16 KB col window (cache-local cursors + writes).
__global__ void bucket_to_csr(const int2* __restrict__ staging, const int* __restrict__ partials,
                              int* __restrict__ cursor, int* __restrict__ col) {
    int b = blockIdx.x;
    int lo = partials[b], hi = partials[b + 1];
    for (int i = lo + threadIdx.x; i < hi; i += blockDim.x) {
        int2 e = staging[i];
        int pos = atomicAdd(&cursor[e.y], 1);
        col[pos] = e.x;
    }
}

// ---- gather aggregation + bias + relu, fused; 1 wave per node, fp16 Z/H ----
// lane = g*16 + l : group g handles edges j+g / j+4+g, lane l owns 8B (4 ch).
__global__ void gather_relu(const __half* __restrict__ Z, const int* __restrict__ rowptr,
                            const int* __restrict__ col, const float* __restrict__ bias,
                            __half* __restrict__ H, int n) {
    int node = (int)((blockIdx.x * blockDim.x + threadIdx.x) >> 6);
    if (node >= n) return;                        // wave-uniform
    int lane = threadIdx.x & 63;
    int g = lane >> 4;
    int l = lane & 15;
    int lo = rowptr[node], hi = rowptr[node + 1];
    const float2* Z2 = reinterpret_cast<const float2*>(Z);   // 16 x 8B per row
    float ax = 0.f, ay = 0.f, az = 0.f, aw = 0.f;
    for (int j = lo; j < hi; j += 8) {
        int j0 = j + g, j1 = j + 4 + g;
        float2 r0 = make_float2(0.f, 0.f), r1 = make_float2(0.f, 0.f);
        if (j0 < hi) r0 = Z2[(size_t)col[j0] * 16 + l];
        if (j1 < hi) r1 = Z2[(size_t)col[j1] * 16 + l];
        __half2 h0 = *(__half2*)&r0.x, h1 = *(__half2*)&r0.y;
        __half2 h2 = *(__half2*)&r1.x, h3 = *(__half2*)&r1.y;
        float2 f0 = __half22float2(h0), f1 = __half22float2(h1);
        float2 f2 = __half22float2(h2), f3 = __half22float2(h3);
        ax += f0.x + f2.x; ay += f0.y + f2.y;
        az += f1.x + f3.x; aw += f1.y + f3.y;
    }
    ax += __shfl_xor(ax, 16); ay += __shfl_xor(ay, 16);
    az += __shfl_xor(az, 16); aw += __shfl_xor(aw, 16);
    ax += __shfl_xor(ax, 32); ay += __shfl_xor(ay, 32);
    az += __shfl_xor(az, 32); aw += __shfl_xor(aw, 32);
    if (g == 0) {
        float2 sr = Z2[(size_t)node * 16 + l];
        __half2 s0 = *(__half2*)&sr.x, s1 = *(__half2*)&sr.y;
        float2 fs0 = __half22float2(s0), fs1 = __half22float2(s1);
        float4 b = reinterpret_cast<const float4*>(bias)[l];
        float ox = fmaxf(fs0.x + ax + b.x, 0.f);
        float oy = fmaxf(fs0.y + ay + b.y, 0.f);
        float oz = fmaxf(fs1.x + az + b.z, 0.f);
        float ow = fmaxf(fs1.y + aw + b.w, 0.f);
        __half2 o0 = __floats2half2_rn(ox, oy);
        __half2 o1 = __floats2half2_rn(oz, ow);
        float2 outv;
        *(__half2*)&outv.x = o0;
        *(__half2*)&outv.y = o1;
        reinterpret_cast<float2*>(H)[(size_t)node * 16 + l] = outv;
    }
}

// ---- fused mean-pool + linear head (batch is sorted), fp16 H ----
__global__ void pool_head(const __half* __restrict__ H, const int* __restrict__ batch,
                          const float* __restrict__ W3, const float* __restrict__ b3,
                          float* __restrict__ out, int n, int ncls) {
    int gidx = blockIdx.x;
    __shared__ int bounds[2];
    __shared__ float row[64];
    int lane = threadIdx.x;                 // 64
    int g = lane >> 4, l = lane & 15;
    if (lane < 2) {
        int target = gidx + lane;           // lower_bound(batch, target)
        int lo = 0, hi = n;
        while (lo < hi) { int m = (lo + hi) >> 1; if (batch[m] < target) lo = m + 1; else hi = m; }
        bounds[lane] = lo;
    }
    __syncthreads();
    int lo = bounds[0], hi = bounds[1];
    const float2* H2 = reinterpret_cast<const float2*>(H);
    float ax = 0.f, ay = 0.f, az = 0.f, aw = 0.f;
    for (int i = lo + g; i < hi; i += 4) {
        float2 raw = H2[(size_t)i * 16 + l];
        __half2 h0 = *(__half2*)&raw.x, h1 = *(__half2*)&raw.y;
        float2 f0 = __half22float2(h0), f1 = __half22float2(h1);
        ax += f0.x; ay += f0.y; az += f1.x; aw += f1.y;
    }
    ax += __shfl_xor(ax, 16); ay += __shfl_xor(ay, 16);
    az += __shfl_xor(az, 16); aw += __shfl_xor(aw, 16);
    ax += __shfl_xor(ax, 32); ay += __shfl_xor(ay, 32);
    az += __shfl_xor(az, 32); aw += __shfl_xor(aw, 32);
    float inv = 1.0f / fmaxf((float)(hi - lo), 1.0f);
    if (g == 0) {
        row[l * 4 + 0] = ax * inv;
        row[l * 4 + 1] = ay * inv;
        row[l * 4 + 2] = az * inv;
        row[l * 4 + 3] = aw * inv;
    }
    __syncthreads();
    if (lane < ncls) {
        float o = b3[lane];
#pragma unroll
        for (int k = 0; k < 64; ++k) o += row[k] * W3[k * ncls + lane];
        out[gidx * ncls + lane] = o;
    }
}

extern "C" void kernel_launch(void* const* d_in, const int* in_sizes, int n_in,
                              void* d_out, int out_size, void* d_ws, size_t ws_size,
                              hipStream_t stream) {
    const float* x     = (const float*)d_in[0];
    const int*   ei    = (const int*)d_in[1];   // [2, E]
    const int*   batch = (const int*)d_in[2];
    const float* W1    = (const float*)d_in[3];
    const float* b1    = (const float*)d_in[4];
    const float* W2    = (const float*)d_in[5];
    const float* b2    = (const float*)d_in[6];
    const float* W3    = (const float*)d_in[7];
    const float* b3    = (const float*)d_in[8];
    float* out = (float*)d_out;

    const int N = in_sizes[0] / N_FEAT;       // 50000
    const int E = in_sizes[1] / 2;            // 800000
    const int NCLS = 10;
    const int G = out_size / NCLS;            // 500
    const int* src = ei;
    const int* dst = ei + E;

    // workspace layout
    int2*   staging = (int2*)d_ws;                        // E pairs (8B align)
    __half* zbuf    = (__half*)(staging + E);             // N*64 fp16
    __half* hbuf    = zbuf + (size_t)N * 64;              // N*64 fp16
    int*    rowptr  = (int*)(hbuf + (size_t)N * 64);      // N+1
    int*    deg     = rowptr + (N + 1);                   // N
    int*    cursor  = deg + N;                            // N
    int*    partials = cursor + N;                        // nb+1
    int*    ccur    = partials + 257;                     // nb
    int*    col     = ccur + 256;                         // E

    const int edgeGrid = (E + 255) / 256;
    const int gemmGrid = (N + 63) / 64;
    const int gatherGrid = (N + 3) / 4;
    const int nb = (N + 255) / 256;           // 196 coarse buckets
    const int scatGrid = (E + CHUNK - 1) / CHUNK;

    // ---- build CSR ----
    hipMemsetAsync(deg, 0, (size_t)N * sizeof(int), stream);
    hist_deg<<<edgeGrid, 256, 0, stream>>>(dst, deg, E);
    scan_partial<<<nb, 256, 0, stream>>>(deg, partials, N);
    scan_offsets<<<1, 256, 0, stream>>>(partials, nb, ccur, rowptr, N, E);
    scan_final<<<nb, 256, 0, stream>>>(deg, partials, rowptr, cursor, N);
    bucket_scatter<<<scatGrid, 256, 0, stream>>>(src, dst, ccur, staging, E);
    bucket_to_csr<<<nb, 256, 0, stream>>>(staging, partials, cursor, col);

    // ---- layer 1 ----
    gemm64<float><<<gemmGrid, 256, 0, stream>>>(x, W1, zbuf, N);
    gather_relu<<<gatherGrid, 256, 0, stream>>>(zbuf, rowptr, col, b1, hbuf, N);

    // ---- layer 2 ----
    gemm64<__half><<<gemmGrid, 256, 0, stream>>>(hbuf, W2, zbuf, N);
    gather_relu<<<gatherGrid, 256, 0, stream>>>(zbuf, rowptr, col, b2, hbuf, N);

    // ---- pool + head ----
    pool_head<<<G, 64, 0, stream>>>(hbuf, batch, W3, b3, out, N, NCLS);
}